// Round 10
// baseline (282.885 us; speedup 1.0000x reference)
//
#include <hip/hip_runtime.h>
#include <hip/hip_bf16.h>

#define THREADS 256

typedef __attribute__((ext_vector_type(8))) short bfrag;     // 8 bf16 = 4 VGPR
typedef __attribute__((ext_vector_type(4))) float f32x4;     // MFMA accumulator

__device__ inline unsigned short f2b(float v) {
    __hip_bfloat16 b = __float2bfloat16(v);
    return *reinterpret_cast<unsigned short*>(&b);
}
__device__ inline float b2f(unsigned short u) {
    return __uint_as_float(((unsigned)u) << 16);
}
__device__ inline float rdv(const void* p, int off, bool isbf) {
    return isbf ? b2f(((const unsigned short*)p)[off]) : ((const float*)p)[off];
}
// 8-element contiguous dot (vector loads, both operands 16B-aligned offsets)
__device__ inline float dot8(const void* W, const void* av, int wbase, int abase, bool isbf) {
    if (isbf) {
        const unsigned short* wp = (const unsigned short*)W + wbase;
        const unsigned short* ap = (const unsigned short*)av + abase;
        ushort4 w0 = *(const ushort4*)wp, w1 = *(const ushort4*)(wp + 4);
        ushort4 a0 = *(const ushort4*)ap, a1 = *(const ushort4*)(ap + 4);
        return b2f(w0.x) * b2f(a0.x) + b2f(w0.y) * b2f(a0.y) +
               b2f(w0.z) * b2f(a0.z) + b2f(w0.w) * b2f(a0.w) +
               b2f(w1.x) * b2f(a1.x) + b2f(w1.y) * b2f(a1.y) +
               b2f(w1.z) * b2f(a1.z) + b2f(w1.w) * b2f(a1.w);
    } else {
        const float* wp = (const float*)W + wbase;
        const float* ap = (const float*)av + abase;
        float4 w0 = *(const float4*)wp, w1 = *(const float4*)(wp + 4);
        float4 a0 = *(const float4*)ap, a1 = *(const float4*)(ap + 4);
        return w0.x * a0.x + w0.y * a0.y + w0.z * a0.z + w0.w * a0.w +
               w1.x * a1.x + w1.y * a1.y + w1.z * a1.z + w1.w * a1.w;
    }
}

struct InPtrs { const void* p[23]; };

// ---------------- fused prep: W->frag-order (+folded es/ed cols via LDS
// phase-A), BN fold, degree count (2 edges/thread). ---------------------------
__global__ void prep_kernel(InPtrs in, int* __restrict__ flag,
                            unsigned short* __restrict__ Wl1, unsigned short* __restrict__ Wl2,
                            unsigned short* __restrict__ WlR, unsigned short* __restrict__ Wl3,
                            float* __restrict__ bnsc1, float* __restrict__ bnsh1,
                            float* __restrict__ bnsc2, float* __restrict__ bnsh2,
                            float* __restrict__ B3f,
                            int N, const int* __restrict__ ei, int* __restrict__ deg8,
                            int E, int DB) {
    int b = blockIdx.x, tid = threadIdx.x;
    if (b >= 30) {
        int stride = DB * 256;
        for (int i = (b - 30) * 256 + tid; i < E + N; i += stride) {
            int d = (i < E) ? ei[E + i] : (i - E);
            int k = (i >> 10) & 7;
            atomicAdd(&deg8[k * N + d], 1);
        }
        return;
    }
    // dtype detect over first 4096 shorts (only these 30 blocks; L2-broadcast)
    __shared__ int sred[4];
    __shared__ float sWes[128 * 8];
    const unsigned short* x = (const unsigned short*)in.p[0];
    int local = 0;
    for (int i = tid; i < 4096; i += 256) {
        unsigned ex = (x[i] >> 7) & 0xFF;
        if (ex == 0xFF || ex >= 134 || (ex > 0 && ex <= 100)) local++;
    }
#pragma unroll
    for (int o = 1; o < 64; o <<= 1) local += __shfl_xor(local, o, 64);
    if ((tid & 63) == 0) sred[tid >> 6] = local;
    __syncthreads();
    bool isbf = !((sred[0] + sred[1] + sred[2] + sred[3]) * 8 > 4096);

    if (b < 29) {
        const void *Wv, *asp = 0, *adp = 0; unsigned short* o; int cols, FH = 0, tt;
        if (b < 9)       { Wv = in.p[2];  asp = in.p[3];  adp = in.p[4];  o = Wl1; cols = 128; FH = 4; tt = b; }
        else if (b < 18) { Wv = in.p[6];  asp = in.p[7];  adp = in.p[8];  o = Wl2; cols = 128; FH = 4; tt = b - 9; }
        else if (b < 26) { Wv = in.p[14];                                 o = WlR; cols = 128;         tt = b - 18; }
        else             { Wv = in.p[10]; asp = in.p[11]; adp = in.p[12]; o = Wl3; cols = 40;  FH = 1; tt = b - 26; }
        // ---- phase A: cooperative fold (parallel dots, vector loads) ----
        bool foldblk = (FH == 4 && tt == 8) || (FH == 1 && tt == 2);
        if (foldblk) {
            if (FH == 4) {
                // 1024 outputs (k in 0..127, dn in 0..7), dot length 32; 4/thread
#pragma unroll
                for (int u = 0; u < 4; ++u) {
                    int od = tid * 4 + u;
                    int k = od >> 3, dn = od & 7;
                    int h = dn < 4 ? dn : dn - 4;
                    const void* av = dn < 4 ? asp : adp;
                    float s = 0.f;
#pragma unroll
                    for (int cc = 0; cc < 32; cc += 8)
                        s += dot8(Wv, av, k * 128 + h * 32 + cc, h * 32 + cc, isbf);
                    sWes[k * 8 + dn] = s;
                }
            } else {
                // 256 outputs (k in 0..127, dn in 0..1), dot length 40; 1/thread
                int k = tid >> 1, dn = tid & 1;
                const void* av = dn ? adp : asp;
                float s = 0.f;
#pragma unroll
                for (int cc = 0; cc < 40; cc += 8)
                    s += dot8(Wv, av, k * 40 + cc, cc, isbf);
                sWes[k * 8 + dn] = s;
            }
            __syncthreads();
        }
        // ---- phase B: fragment-order write ----
        int id = tt * 256 + tid;
        int ks = (id >> 6) & 3, l = id & 63;
        int q = l >> 4, n = l & 15;
        int c = tt * 16 + n;
#pragma unroll
        for (int j = 0; j < 8; ++j) {
            int k = ks * 32 + q * 8 + j;
            float v = 0.f;
            if (c < cols) v = rdv(Wv, k * cols + c, isbf);
            else if (FH && c < cols + 2 * FH) v = sWes[k * 8 + (c - cols)];
            o[id * 8 + j] = f2b(v);
        }
    } else {
        int c = tid;
        if (c < 128) {
            float s = rdv(in.p[15], c, isbf) * rsqrtf(rdv(in.p[18], c, isbf) + 1e-5f);
            bnsc1[c] = s;
            bnsh1[c] = rdv(in.p[16], c, isbf) - rdv(in.p[17], c, isbf) * s +
                       rdv(in.p[5], c, isbf) * s;
        } else {
            int d = c - 128;
            float s = rdv(in.p[19], d, isbf) * rsqrtf(rdv(in.p[22], d, isbf) + 1e-5f);
            bnsc2[d] = s;
            bnsh2[d] = rdv(in.p[20], d, isbf) - rdv(in.p[21], d, isbf) * s +
                       rdv(in.p[9], d, isbf) * s;
            if (d < 40) B3f[d] = rdv(in.p[13], d, isbf);
        }
        if (tid == 0) *flag = isbf ? 1 : 0;
    }
}

// ---------------- CSR scan stages (8-copy aware) ----------------
__global__ void bsum_kernel(const int* __restrict__ deg8, int* __restrict__ bsum, int N) {
    int idx = blockIdx.x * 256 + threadIdx.x;
    int lane = threadIdx.x & 63, wv = threadIdx.x >> 6;
    int v = 0;
    if (idx < N) {
#pragma unroll
        for (int k = 0; k < 8; ++k) v += deg8[k * N + idx];
    }
#pragma unroll
    for (int o = 1; o < 64; o <<= 1) v += __shfl_xor(v, o, 64);
    __shared__ int ws[4];
    if (lane == 0) ws[wv] = v;
    __syncthreads();
    if (threadIdx.x == 0) bsum[blockIdx.x] = ws[0] + ws[1] + ws[2] + ws[3];
}

__global__ __launch_bounds__(1024) void bscan_kernel(const int* __restrict__ bsum,
                                                     int* __restrict__ boff, int nb) {
    __shared__ int ws[16];
    int tid = threadIdx.x, lane = tid & 63, wv = tid >> 6;
    int v = (tid < nb) ? bsum[tid] : 0;
    int sc = v;
#pragma unroll
    for (int o = 1; o < 64; o <<= 1) {
        int t = __shfl_up(sc, o, 64);
        if (lane >= o) sc += t;
    }
    if (lane == 63) ws[wv] = sc;
    __syncthreads();
    int add = 0;
#pragma unroll
    for (int k = 0; k < 16; ++k) add += (k < wv) ? ws[k] : 0;
    if (tid < nb) boff[tid] = add + sc - v;
}

__global__ void scanw_kernel(const int* __restrict__ deg8, const int* __restrict__ boff,
                             int* __restrict__ row_ptr, int* __restrict__ posk, int N) {
    int idx = blockIdx.x * 256 + threadIdx.x;
    int lane = threadIdx.x & 63, wv = threadIdx.x >> 6;
    int vk[8];
    int v = 0;
    if (idx < N) {
#pragma unroll
        for (int k = 0; k < 8; ++k) { vk[k] = deg8[k * N + idx]; v += vk[k]; }
    } else {
#pragma unroll
        for (int k = 0; k < 8; ++k) vk[k] = 0;
    }
    int sc = v;
#pragma unroll
    for (int o = 1; o < 64; o <<= 1) {
        int t = __shfl_up(sc, o, 64);
        if (lane >= o) sc += t;
    }
    __shared__ int ws[4];
    if (lane == 63) ws[wv] = sc;
    __syncthreads();
    int add = boff[blockIdx.x];
#pragma unroll
    for (int k = 0; k < 4; ++k) add += (k < wv) ? ws[k] : 0;
    int excl = add + sc - v;
    if (idx < N) {
        row_ptr[idx + 1] = excl + v;
        int run = excl;
#pragma unroll
        for (int k = 0; k < 8; ++k) { posk[k * N + idx] = run; run += vk[k]; }
    }
    if (idx == 0) row_ptr[0] = 0;
}

// ---------------- fused: gemm_dual (blocks < GG) ∥ scatter (blocks >= GG) ----
// LDS halved to 32 KB (only W1 staged; WgR read from global like accE tile)
// so scatter blocks keep 4-5 blocks/CU occupancy.
__global__ __launch_bounds__(256) void fused_sg(
    const void* __restrict__ Ain, const int* __restrict__ flag,
    const unsigned short* __restrict__ Wg1, const unsigned short* __restrict__ WgR,
    unsigned short* __restrict__ xwb, unsigned short* __restrict__ resb,
    float* __restrict__ es, float* __restrict__ ed,
    const int* __restrict__ ei, int* __restrict__ posk, int* __restrict__ csr,
    int E, int N, int GG, int DB) {
    int tid = threadIdx.x;
    if ((int)blockIdx.x >= GG) {
        // ---- scatter: same k mapping + index space as degree count ----
        int sb = blockIdx.x - GG;
        int stride = DB * 256;
        for (int i = sb * 256 + tid; i < E + N; i += stride) {
            int s, d;
            if (i < E) { s = ei[i]; d = ei[E + i]; }
            else { s = i - E; d = s; }
            int k = (i >> 10) & 7;
            int p = atomicAdd(&posk[k * N + d], 1);
            csr[p] = s;
        }
        return;
    }
    __shared__ __align__(16) unsigned short Wls[8 * 2048];
    {
        const float4* s1 = (const float4*)Wg1;
        float4* dst = (float4*)Wls;
#pragma unroll
        for (int i = 0; i < 8; ++i) dst[tid + i * 256] = s1[tid + i * 256];
    }
    bool isbf = (*flag != 0);
    __syncthreads();
    int w = tid >> 6, lane = tid & 63;
    int n = lane & 15, q = lane >> 4;
    int row0 = blockIdx.x * 64 + w * 16;
    int ar = row0 + n; ar = ar < N ? ar : N - 1;
    bfrag a[4];
    if (isbf) {
        const unsigned short* arow = (const unsigned short*)Ain + (size_t)ar * 128;
#pragma unroll
        for (int ks = 0; ks < 4; ++ks)
            a[ks] = *reinterpret_cast<const bfrag*>(arow + ks * 32 + q * 8);
    } else {
        const float* arow = (const float*)Ain + (size_t)ar * 128;
#pragma unroll
        for (int ks = 0; ks < 4; ++ks) {
            float4 f0 = *reinterpret_cast<const float4*>(arow + ks * 32 + q * 8);
            float4 f1 = *reinterpret_cast<const float4*>(arow + ks * 32 + q * 8 + 4);
            bfrag t;
            t[0] = (short)f2b(f0.x); t[1] = (short)f2b(f0.y);
            t[2] = (short)f2b(f0.z); t[3] = (short)f2b(f0.w);
            t[4] = (short)f2b(f1.x); t[5] = (short)f2b(f1.y);
            t[6] = (short)f2b(f1.z); t[7] = (short)f2b(f1.w);
            a[ks] = t;
        }
    }
    f32x4 acc[16], accE;
#pragma unroll
    for (int t = 0; t < 16; ++t) acc[t] = (f32x4){0.f, 0.f, 0.f, 0.f};
    accE = (f32x4){0.f, 0.f, 0.f, 0.f};
#pragma unroll
    for (int ks = 0; ks < 4; ++ks) {
#pragma unroll
        for (int t = 0; t < 8; ++t) {
            bfrag b = *reinterpret_cast<const bfrag*>(&Wls[((t * 4 + ks) * 64 + lane) * 8]);
            acc[t] = __builtin_amdgcn_mfma_f32_16x16x32_bf16(a[ks], b, acc[t], 0, 0, 0);
        }
        // folded es/ed tile read straight from global (L2-hot broadcast)
        bfrag be = *reinterpret_cast<const bfrag*>(Wg1 + ((size_t)(32 + ks) * 64 + lane) * 8);
        accE = __builtin_amdgcn_mfma_f32_16x16x32_bf16(a[ks], be, accE, 0, 0, 0);
        // Wres tiles also from global (L2-hot, lane-contiguous 1 KB/wave)
#pragma unroll
        for (int t = 0; t < 8; ++t) {
            bfrag b = *reinterpret_cast<const bfrag*>(WgR + ((size_t)((t * 4 + ks) * 64 + lane)) * 8);
            acc[8 + t] = __builtin_amdgcn_mfma_f32_16x16x32_bf16(a[ks], b, acc[8 + t], 0, 0, 0);
        }
    }
#pragma unroll
    for (int r = 0; r < 4; ++r) {
        int row = row0 + q * 4 + r;
        if (row < N) {
            if (n < 4) es[(size_t)row * 4 + n] = accE[r];
            else if (n < 8) ed[(size_t)row * 4 + (n - 4)] = accE[r];
        }
    }
#pragma unroll
    for (int t = 0; t < 8; ++t) {
        int col = t * 16 + n;
#pragma unroll
        for (int r = 0; r < 4; ++r) {
            int row = row0 + q * 4 + r;
            if (row < N) {
                xwb[(size_t)row * 128 + col] = f2b(acc[t][r]);
                resb[(size_t)row * 128 + col] = f2b(acc[8 + t][r]);
            }
        }
    }
}

// ---------------- MFMA GEMM: [N,128]bf16 @ [128,cols+fold]bf16 ----------------
// es/ed come out of MFMA tile TE (folded weight columns) -> no shfl epilogue.
template <int COLT, int HEADS, int ESCOL>
__global__ __launch_bounds__(256) void gemm_mfma(
    const unsigned short* __restrict__ A, const unsigned short* __restrict__ Wg,
    unsigned short* __restrict__ out, int ldc, int cols,
    float* __restrict__ es, float* __restrict__ ed, int N) {
    __shared__ __align__(16) unsigned short Wls[COLT * 2048];
    int tid = threadIdx.x;
    {
        const float4* src = (const float4*)Wg;
        float4* dst = (float4*)Wls;
#pragma unroll
        for (int i = 0; i < COLT; ++i) dst[tid + i * 256] = src[tid + i * 256];
    }
    __syncthreads();
    int w = tid >> 6, lane = tid & 63;
    int n = lane & 15, q = lane >> 4;
    int row0 = blockIdx.x * 64 + w * 16;
    int ar = row0 + n; ar = ar < N ? ar : N - 1;   // clamp: OOB rows harmless
    f32x4 acc[COLT];
#pragma unroll
    for (int t = 0; t < COLT; ++t) acc[t] = (f32x4){0.f, 0.f, 0.f, 0.f};
    const unsigned short* arow = A + (size_t)ar * 128;
#pragma unroll
    for (int ks = 0; ks < 4; ++ks) {
        bfrag a = *reinterpret_cast<const bfrag*>(arow + ks * 32 + q * 8);
#pragma unroll
        for (int t = 0; t < COLT; ++t) {
            bfrag b = *reinterpret_cast<const bfrag*>(&Wls[((t * 4 + ks) * 64 + lane) * 8]);
            acc[t] = __builtin_amdgcn_mfma_f32_16x16x32_bf16(a, b, acc[t], 0, 0, 0);
        }
    }
    constexpr int TE = ESCOL >> 4, NE = ESCOL & 15;
    int dn = n - NE;
#pragma unroll
    for (int r = 0; r < 4; ++r) {
        int row = row0 + q * 4 + r;
        if (row < N) {
            if (dn >= 0 && dn < HEADS) es[(size_t)row * HEADS + dn] = acc[TE][r];
            else if (dn >= HEADS && dn < 2 * HEADS)
                ed[(size_t)row * HEADS + (dn - HEADS)] = acc[TE][r];
        }
    }
#pragma unroll
    for (int t = 0; t < COLT; ++t) {
        int col = t * 16 + n;
        if (col < cols) {
#pragma unroll
            for (int r = 0; r < 4; ++r) {
                int row = row0 + q * 4 + r;
                if (row < N) out[(size_t)row * ldc + col] = f2b(acc[t][r]);
            }
        }
    }
}

// ---------------- agg layers 1-2 + fused BN/bias/residual/ELU ----------------
__global__ __launch_bounds__(256) void agg128_fused(
    const unsigned short* __restrict__ xwb, const float* __restrict__ es,
    const float* __restrict__ ed, const int* __restrict__ row_ptr,
    const int* __restrict__ csr, const float* __restrict__ bnsc,
    const float* __restrict__ bnsh, const unsigned short* __restrict__ resb,
    unsigned short* __restrict__ outb, int N) {
    int w = threadIdx.x >> 6, lane = threadIdx.x & 63;
    int node = blockIdx.x * 4 + w;
    if (node >= N) return;
    int h = lane >> 4;
    int c0 = lane * 2;
    // hoisted independent epilogue loads (overlap with gather chain)
    float edl = ed[node * 4 + h];
    float2 sc = *(const float2*)(bnsc + c0);
    float2 sh = *(const float2*)(bnsh + c0);
    unsigned ur = *(const unsigned*)(resb + (size_t)node * 128 + c0);
    int start = __builtin_amdgcn_readfirstlane(row_ptr[node]);
    int end = __builtin_amdgcn_readfirstlane(row_ptr[node + 1]);
    float den = 0.f, a0 = 0.f, a1 = 0.f;
    for (int jb = start; jb < end; jb += 16) {
        int su[16];
#pragma unroll
        for (int u = 0; u < 16; ++u) {
            int idx = jb + u;
            idx = idx < end - 1 ? idx : end - 1;
            su[u] = csr[idx];                       // uniform addr -> s_load
        }
        unsigned uu[16];
        float ev[16];
#pragma unroll
        for (int u = 0; u < 16; ++u) {
            uu[u] = *(const unsigned*)(xwb + (size_t)su[u] * 128 + c0);
            ev[u] = es[su[u] * 4 + h];
        }
#pragma unroll
        for (int u = 0; u < 16; ++u) {
            float e = ev[u] + edl;
            e = e > 0.f ? e : 0.2f * e;
            float wg = __expf(e);
            wg = (jb + u < end) ? wg : 0.f;         // uniform cond, branch-free
            den += wg;
            a0 = fmaf(wg, __uint_as_float(uu[u] << 16), a0);
            a1 = fmaf(wg, __uint_as_float(uu[u] & 0xffff0000u), a1);
        }
    }
    float inv = 1.f / den;
    float v0 = fmaf(a0 * inv, sc.x, sh.x) + __uint_as_float(ur << 16);
    float v1 = fmaf(a1 * inv, sc.y, sh.y) + __uint_as_float(ur & 0xffff0000u);
    v0 = v0 > 0.f ? v0 : expm1f(v0);
    v1 = v1 > 0.f ? v1 : expm1f(v1);
    unsigned pk = (unsigned)f2b(v0) | ((unsigned)f2b(v1) << 16);
    *(unsigned*)(outb + (size_t)node * 128 + c0) = pk;
}

// ---------------- layer-3 agg (H=1, 40ch) ----------------
__global__ __launch_bounds__(256) void agg40_kernel(
    const unsigned short* __restrict__ xw3b, const float* __restrict__ es3,
    const float* __restrict__ ed3, const int* __restrict__ row_ptr,
    const int* __restrict__ csr, const float* __restrict__ b3,
    void* __restrict__ out, const int* __restrict__ flag, int N) {
    int w = threadIdx.x >> 6, lane = threadIdx.x & 63;
    int node = blockIdx.x * 4 + w;
    if (node >= N) return;
    int i16 = lane & 15;
    int g = lane >= 40 ? 2 : (lane >= 20 ? 1 : 0);
    int cp = lane - g * 20;
    int c0 = cp * 2; c0 = c0 > 38 ? 38 : c0;
    // hoisted independent loads
    float edl = ed3[node];
    float b30 = b3[c0], b31 = b3[c0 + 1];
    int start = row_ptr[node], end = row_ptr[node + 1];
    float den = 0.f, a0 = 0.f, a1 = 0.f;
    for (int jb = start; jb < end; jb += 16) {
        int cnt = end - jb; cnt = cnt < 16 ? cnt : 16;
        int sv = csr[jb + (i16 < cnt ? i16 : 0)];
        unsigned uu[6];
#pragma unroll
        for (int t = 0; t < 6; ++t) {
            int slot = 3 * t + g; slot = slot < 15 ? slot : 15;
            int s = __shfl(sv, slot, 64);
            uu[t] = *(const unsigned*)(xw3b + (size_t)s * 40 + c0);
        }
        float wgl = 0.f;
        if (i16 < cnt) {
            float e = es3[sv] + edl;
            e = e > 0.f ? e : 0.2f * e;
            wgl = __expf(e);
        }
        float d = wgl;
        d += __shfl_xor(d, 1, 64);
        d += __shfl_xor(d, 2, 64);
        d += __shfl_xor(d, 4, 64);
        d += __shfl_xor(d, 8, 64);
        den += d;
#pragma unroll
        for (int t = 0; t < 6; ++t) {
            int slot = 3 * t + g;
            int sl = slot < 15 ? slot : 15;
            float wg = __shfl(wgl, sl, 64);
            if (slot >= cnt) wg = 0.f;
            a0 = fmaf(wg, __uint_as_float(uu[t] << 16), a0);
            a1 = fmaf(wg, __uint_as_float(uu[t] & 0xffff0000u), a1);
        }
    }
    float t0 = __shfl(a0, (lane + 20) & 63, 64);
    float t1 = __shfl(a0, (lane + 40) & 63, 64);
    float u0 = __shfl(a1, (lane + 20) & 63, 64);
    float u1 = __shfl(a1, (lane + 40) & 63, 64);
    a0 += t0 + t1;
    a1 += u0 + u1;
    if (lane < 20) {
        float inv = 1.f / den;
        float v0 = a0 * inv + b30;
        float v1 = a1 * inv + b31;
        size_t eoff = (size_t)node * 40 + c0;
        if (*flag) {
            unsigned pk = (unsigned)f2b(v0) | ((unsigned)f2b(v1) << 16);
            *(unsigned*)((unsigned short*)out + eoff) = pk;
        } else {
            *(float2*)((float*)out + eoff) = make_float2(v0, v1);
        }
    }
}

extern "C" void kernel_launch(void* const* d_in, const int* in_sizes, int n_in,
                              void* d_out, int out_size, void* d_ws, size_t ws_size,
                              hipStream_t stream) {
    (void)n_in; (void)out_size; (void)ws_size;
    const int N = in_sizes[0] / 128;
    const int E = in_sizes[1] / 2;
    const int EPN = E + N;
    const int NB = (N + 255) / 256;
    const int DB = (EPN + 511) / 512;     // 2 edges/thread blocks
    char* base = (char*)d_ws;
    size_t off = 0;
    auto alloc = [&](size_t bytes) -> char* {
        char* p = base + off;
        off = (off + bytes + 255) & ~(size_t)255;
        return p;
    };
    int* flag = (int*)alloc(4);
    int* deg8 = (int*)alloc((size_t)N * 8 * 4);     // zeroed each launch
    int* posk = (int*)alloc((size_t)N * 8 * 4);
    int* row_ptr = (int*)alloc((size_t)(N + 1) * 4);
    int* bsum = (int*)alloc((size_t)NB * 4);
    int* boff = (int*)alloc((size_t)NB * 4);
    int* csr = (int*)alloc((size_t)EPN * 4);
    float* bnsc1 = (float*)alloc(512); float* bnsh1 = (float*)alloc(512);
    float* bnsc2 = (float*)alloc(512); float* bnsh2 = (float*)alloc(512);
    float* B3f = (float*)alloc(256);
    unsigned short* Wl1 = (unsigned short*)alloc(36864);  // 9 tiles
    unsigned short* Wl2 = (unsigned short*)alloc(36864);  // 9 tiles
    unsigned short* WlR = (unsigned short*)alloc(32768);  // 8 tiles
    unsigned short* Wl3 = (unsigned short*)alloc(12288);  // 3 tiles
    unsigned short* xwb = (unsigned short*)alloc((size_t)N * 128 * 2);  // also xw3
    unsigned short* h1b = (unsigned short*)alloc((size_t)N * 128 * 2);
    unsigned short* resb = (unsigned short*)alloc((size_t)N * 128 * 2); // later h2b
    float* es = (float*)alloc((size_t)N * 4 * 4);   // [node*4+h]
    float* ed = (float*)alloc((size_t)N * 4 * 4);

    const int* ei = (const int*)d_in[1];

    hipMemsetAsync(deg8, 0, (size_t)N * 8 * 4, stream);

    InPtrs ip;
    for (int t = 0; t < 23; t++) ip.p[t] = d_in[t];
    prep_kernel<<<30 + DB, THREADS, 0, stream>>>(ip, flag, Wl1, Wl2, WlR, Wl3,
                                                 bnsc1, bnsh1, bnsc2, bnsh2,
                                                 B3f, N, ei, deg8, E, DB);

    bsum_kernel<<<NB, 256, 0, stream>>>(deg8, bsum, N);
    bscan_kernel<<<1, 1024, 0, stream>>>(bsum, boff, NB);
    scanw_kernel<<<NB, 256, 0, stream>>>(deg8, boff, row_ptr, posk, N);

    int gemmGrid = (N + 63) / 64;
    int aggGrid = (N + 3) / 4;

    // layer 1 GEMM fused with CSR scatter (independent work, one dispatch)
    fused_sg<<<gemmGrid + DB, 256, 0, stream>>>(d_in[0], flag, Wl1, WlR,
                                                xwb, resb, es, ed,
                                                ei, posk, csr, E, N, gemmGrid, DB);
    agg128_fused<<<aggGrid, 256, 0, stream>>>(xwb, es, ed, row_ptr, csr,
                                              bnsc1, bnsh1, resb, h1b, N);
    // layer 2
    gemm_mfma<9, 4, 128><<<gemmGrid, 256, 0, stream>>>(
        h1b, Wl2, xwb, 128, 128, es, ed, N);
    unsigned short* h2b = resb;  // resb free after layer-1 agg
    agg128_fused<<<aggGrid, 256, 0, stream>>>(xwb, es, ed, row_ptr, csr,
                                              bnsc2, bnsh2, h1b, h2b, N);
    // layer 3 (es/ed folded into cols 40,41 of tile 2)
    gemm_mfma<3, 1, 40><<<gemmGrid, 256, 0, stream>>>(
        h2b, Wl3, xwb, 40, 40, es, ed, N);
    agg40_kernel<<<aggGrid, 256, 0, stream>>>(xwb, es, ed, row_ptr, csr, B3f,
                                              d_out, flag, N);
}

// Round 21
// 280.209 us; speedup vs baseline: 1.0095x; 1.0095x over previous
//
#include <hip/hip_runtime.h>
#include <hip/hip_bf16.h>

#define THREADS 256

typedef __attribute__((ext_vector_type(8))) short bfrag;     // 8 bf16 = 4 VGPR
typedef __attribute__((ext_vector_type(4))) float f32x4;     // MFMA accumulator

__device__ inline unsigned short f2b(float v) {
    __hip_bfloat16 b = __float2bfloat16(v);
    return *reinterpret_cast<unsigned short*>(&b);
}
__device__ inline float b2f(unsigned short u) {
    return __uint_as_float(((unsigned)u) << 16);
}
__device__ inline float rdv(const void* p, int off, bool isbf) {
    return isbf ? b2f(((const unsigned short*)p)[off]) : ((const float*)p)[off];
}
// 8-element contiguous dot (vector loads, both operands 16B-aligned offsets)
__device__ inline float dot8(const void* W, const void* av, int wbase, int abase, bool isbf) {
    if (isbf) {
        const unsigned short* wp = (const unsigned short*)W + wbase;
        const unsigned short* ap = (const unsigned short*)av + abase;
        ushort4 w0 = *(const ushort4*)wp, w1 = *(const ushort4*)(wp + 4);
        ushort4 a0 = *(const ushort4*)ap, a1 = *(const ushort4*)(ap + 4);
        return b2f(w0.x) * b2f(a0.x) + b2f(w0.y) * b2f(a0.y) +
               b2f(w0.z) * b2f(a0.z) + b2f(w0.w) * b2f(a0.w) +
               b2f(w1.x) * b2f(a1.x) + b2f(w1.y) * b2f(a1.y) +
               b2f(w1.z) * b2f(a1.z) + b2f(w1.w) * b2f(a1.w);
    } else {
        const float* wp = (const float*)W + wbase;
        const float* ap = (const float*)av + abase;
        float4 w0 = *(const float4*)wp, w1 = *(const float4*)(wp + 4);
        float4 a0 = *(const float4*)ap, a1 = *(const float4*)(ap + 4);
        return w0.x * a0.x + w0.y * a0.y + w0.z * a0.z + w0.w * a0.w +
               w1.x * a1.x + w1.y * a1.y + w1.z * a1.z + w1.w * a1.w;
    }
}

struct InPtrs { const void* p[23]; };

// ---------------- fused prep: W->frag-order (+folded es/ed cols via LDS
// phase-A), BN fold, degree count (2 edges/thread). ---------------------------
__global__ void prep_kernel(InPtrs in, int* __restrict__ flag,
                            unsigned short* __restrict__ Wl1, unsigned short* __restrict__ Wl2,
                            unsigned short* __restrict__ WlR, unsigned short* __restrict__ Wl3,
                            float* __restrict__ bnsc1, float* __restrict__ bnsh1,
                            float* __restrict__ bnsc2, float* __restrict__ bnsh2,
                            float* __restrict__ B3f,
                            int N, const int* __restrict__ ei, int* __restrict__ deg8,
                            int E, int DB) {
    int b = blockIdx.x, tid = threadIdx.x;
    if (b >= 30) {
        int stride = DB * 256;
        for (int i = (b - 30) * 256 + tid; i < E + N; i += stride) {
            int d = (i < E) ? ei[E + i] : (i - E);
            int k = (i >> 10) & 7;
            atomicAdd(&deg8[k * N + d], 1);
        }
        return;
    }
    // dtype detect over first 4096 shorts (only these 30 blocks; L2-broadcast)
    __shared__ int sred[4];
    __shared__ float sWes[128 * 8];
    const unsigned short* x = (const unsigned short*)in.p[0];
    int local = 0;
    for (int i = tid; i < 4096; i += 256) {
        unsigned ex = (x[i] >> 7) & 0xFF;
        if (ex == 0xFF || ex >= 134 || (ex > 0 && ex <= 100)) local++;
    }
#pragma unroll
    for (int o = 1; o < 64; o <<= 1) local += __shfl_xor(local, o, 64);
    if ((tid & 63) == 0) sred[tid >> 6] = local;
    __syncthreads();
    bool isbf = !((sred[0] + sred[1] + sred[2] + sred[3]) * 8 > 4096);

    if (b < 29) {
        const void *Wv, *asp = 0, *adp = 0; unsigned short* o; int cols, FH = 0, tt;
        if (b < 9)       { Wv = in.p[2];  asp = in.p[3];  adp = in.p[4];  o = Wl1; cols = 128; FH = 4; tt = b; }
        else if (b < 18) { Wv = in.p[6];  asp = in.p[7];  adp = in.p[8];  o = Wl2; cols = 128; FH = 4; tt = b - 9; }
        else if (b < 26) { Wv = in.p[14];                                 o = WlR; cols = 128;         tt = b - 18; }
        else             { Wv = in.p[10]; asp = in.p[11]; adp = in.p[12]; o = Wl3; cols = 40;  FH = 1; tt = b - 26; }
        // ---- phase A: cooperative fold (parallel dots, vector loads) ----
        bool foldblk = (FH == 4 && tt == 8) || (FH == 1 && tt == 2);
        if (foldblk) {
            if (FH == 4) {
#pragma unroll
                for (int u = 0; u < 4; ++u) {
                    int od = tid * 4 + u;
                    int k = od >> 3, dn = od & 7;
                    int h = dn < 4 ? dn : dn - 4;
                    const void* av = dn < 4 ? asp : adp;
                    float s = 0.f;
#pragma unroll
                    for (int cc = 0; cc < 32; cc += 8)
                        s += dot8(Wv, av, k * 128 + h * 32 + cc, h * 32 + cc, isbf);
                    sWes[k * 8 + dn] = s;
                }
            } else {
                int k = tid >> 1, dn = tid & 1;
                const void* av = dn ? adp : asp;
                float s = 0.f;
#pragma unroll
                for (int cc = 0; cc < 40; cc += 8)
                    s += dot8(Wv, av, k * 40 + cc, cc, isbf);
                sWes[k * 8 + dn] = s;
            }
            __syncthreads();
        }
        // ---- phase B: fragment-order write ----
        int id = tt * 256 + tid;
        int ks = (id >> 6) & 3, l = id & 63;
        int q = l >> 4, n = l & 15;
        int c = tt * 16 + n;
#pragma unroll
        for (int j = 0; j < 8; ++j) {
            int k = ks * 32 + q * 8 + j;
            float v = 0.f;
            if (c < cols) v = rdv(Wv, k * cols + c, isbf);
            else if (FH && c < cols + 2 * FH) v = sWes[k * 8 + (c - cols)];
            o[id * 8 + j] = f2b(v);
        }
    } else {
        int c = tid;
        if (c < 128) {
            float s = rdv(in.p[15], c, isbf) * rsqrtf(rdv(in.p[18], c, isbf) + 1e-5f);
            bnsc1[c] = s;
            bnsh1[c] = rdv(in.p[16], c, isbf) - rdv(in.p[17], c, isbf) * s +
                       rdv(in.p[5], c, isbf) * s;
        } else {
            int d = c - 128;
            float s = rdv(in.p[19], d, isbf) * rsqrtf(rdv(in.p[22], d, isbf) + 1e-5f);
            bnsc2[d] = s;
            bnsh2[d] = rdv(in.p[20], d, isbf) - rdv(in.p[21], d, isbf) * s +
                       rdv(in.p[9], d, isbf) * s;
            if (d < 40) B3f[d] = rdv(in.p[13], d, isbf);
        }
        if (tid == 0) *flag = isbf ? 1 : 0;
    }
}

// ---------------- CSR scan stages (8-copy aware) ----------------
__global__ void bsum_kernel(const int* __restrict__ deg8, int* __restrict__ bsum, int N) {
    int idx = blockIdx.x * 256 + threadIdx.x;
    int lane = threadIdx.x & 63, wv = threadIdx.x >> 6;
    int v = 0;
    if (idx < N) {
#pragma unroll
        for (int k = 0; k < 8; ++k) v += deg8[k * N + idx];
    }
#pragma unroll
    for (int o = 1; o < 64; o <<= 1) v += __shfl_xor(v, o, 64);
    __shared__ int ws[4];
    if (lane == 0) ws[wv] = v;
    __syncthreads();
    if (threadIdx.x == 0) bsum[blockIdx.x] = ws[0] + ws[1] + ws[2] + ws[3];
}

__global__ __launch_bounds__(1024) void bscan_kernel(const int* __restrict__ bsum,
                                                     int* __restrict__ boff, int nb) {
    __shared__ int ws[16];
    int tid = threadIdx.x, lane = tid & 63, wv = tid >> 6;
    int v = (tid < nb) ? bsum[tid] : 0;
    int sc = v;
#pragma unroll
    for (int o = 1; o < 64; o <<= 1) {
        int t = __shfl_up(sc, o, 64);
        if (lane >= o) sc += t;
    }
    if (lane == 63) ws[wv] = sc;
    __syncthreads();
    int add = 0;
#pragma unroll
    for (int k = 0; k < 16; ++k) add += (k < wv) ? ws[k] : 0;
    if (tid < nb) boff[tid] = add + sc - v;
}

__global__ void scanw_kernel(const int* __restrict__ deg8, const int* __restrict__ boff,
                             int* __restrict__ row_ptr, int* __restrict__ posk, int N) {
    int idx = blockIdx.x * 256 + threadIdx.x;
    int lane = threadIdx.x & 63, wv = threadIdx.x >> 6;
    int vk[8];
    int v = 0;
    if (idx < N) {
#pragma unroll
        for (int k = 0; k < 8; ++k) { vk[k] = deg8[k * N + idx]; v += vk[k]; }
    } else {
#pragma unroll
        for (int k = 0; k < 8; ++k) vk[k] = 0;
    }
    int sc = v;
#pragma unroll
    for (int o = 1; o < 64; o <<= 1) {
        int t = __shfl_up(sc, o, 64);
        if (lane >= o) sc += t;
    }
    __shared__ int ws[4];
    if (lane == 63) ws[wv] = sc;
    __syncthreads();
    int add = boff[blockIdx.x];
#pragma unroll
    for (int k = 0; k < 4; ++k) add += (k < wv) ? ws[k] : 0;
    int excl = add + sc - v;
    if (idx < N) {
        row_ptr[idx + 1] = excl + v;
        int run = excl;
#pragma unroll
        for (int k = 0; k < 8; ++k) { posk[k * N + idx] = run; run += vk[k]; }
    }
    if (idx == 0) row_ptr[0] = 0;
}

// ---------------- fused: gemm_dual (blocks < GG) ∥ scatter (blocks >= GG) ----
// r9-proven version: full 64KB LDS staging (W1 + WgR).
__global__ __launch_bounds__(256) void fused_sg(
    const void* __restrict__ Ain, const int* __restrict__ flag,
    const unsigned short* __restrict__ Wg1, const unsigned short* __restrict__ WgR,
    unsigned short* __restrict__ xwb, unsigned short* __restrict__ resb,
    float* __restrict__ es, float* __restrict__ ed,
    const int* __restrict__ ei, int* __restrict__ posk, int* __restrict__ csr,
    int E, int N, int GG, int DB) {
    int tid = threadIdx.x;
    if ((int)blockIdx.x >= GG) {
        // ---- scatter: same k mapping + index space as degree count ----
        int sb = blockIdx.x - GG;
        int stride = DB * 256;
        for (int i = sb * 256 + tid; i < E + N; i += stride) {
            int s, d;
            if (i < E) { s = ei[i]; d = ei[E + i]; }
            else { s = i - E; d = s; }
            int k = (i >> 10) & 7;
            int p = atomicAdd(&posk[k * N + d], 1);
            csr[p] = s;
        }
        return;
    }
    __shared__ __align__(16) unsigned short Wls[16 * 2048];
    {
        const float4* s1 = (const float4*)Wg1;
        const float4* s2 = (const float4*)WgR;
        float4* dst = (float4*)Wls;
#pragma unroll
        for (int i = 0; i < 8; ++i) dst[tid + i * 256] = s1[tid + i * 256];
#pragma unroll
        for (int i = 0; i < 8; ++i) dst[2048 + tid + i * 256] = s2[tid + i * 256];
    }
    bool isbf = (*flag != 0);
    __syncthreads();
    int w = tid >> 6, lane = tid & 63;
    int n = lane & 15, q = lane >> 4;
    int row0 = blockIdx.x * 64 + w * 16;
    int ar = row0 + n; ar = ar < N ? ar : N - 1;
    bfrag a[4];
    if (isbf) {
        const unsigned short* arow = (const unsigned short*)Ain + (size_t)ar * 128;
#pragma unroll
        for (int ks = 0; ks < 4; ++ks)
            a[ks] = *reinterpret_cast<const bfrag*>(arow + ks * 32 + q * 8);
    } else {
        const float* arow = (const float*)Ain + (size_t)ar * 128;
#pragma unroll
        for (int ks = 0; ks < 4; ++ks) {
            float4 f0 = *reinterpret_cast<const float4*>(arow + ks * 32 + q * 8);
            float4 f1 = *reinterpret_cast<const float4*>(arow + ks * 32 + q * 8 + 4);
            bfrag t;
            t[0] = (short)f2b(f0.x); t[1] = (short)f2b(f0.y);
            t[2] = (short)f2b(f0.z); t[3] = (short)f2b(f0.w);
            t[4] = (short)f2b(f1.x); t[5] = (short)f2b(f1.y);
            t[6] = (short)f2b(f1.z); t[7] = (short)f2b(f1.w);
            a[ks] = t;
        }
    }
    f32x4 acc[16], accE;
#pragma unroll
    for (int t = 0; t < 16; ++t) acc[t] = (f32x4){0.f, 0.f, 0.f, 0.f};
    accE = (f32x4){0.f, 0.f, 0.f, 0.f};
#pragma unroll
    for (int ks = 0; ks < 4; ++ks) {
#pragma unroll
        for (int t = 0; t < 8; ++t) {
            bfrag b = *reinterpret_cast<const bfrag*>(&Wls[((t * 4 + ks) * 64 + lane) * 8]);
            acc[t] = __builtin_amdgcn_mfma_f32_16x16x32_bf16(a[ks], b, acc[t], 0, 0, 0);
        }
        // folded es/ed tile read straight from global (L2-hot broadcast)
        bfrag be = *reinterpret_cast<const bfrag*>(Wg1 + ((size_t)(32 + ks) * 64 + lane) * 8);
        accE = __builtin_amdgcn_mfma_f32_16x16x32_bf16(a[ks], be, accE, 0, 0, 0);
#pragma unroll
        for (int t = 0; t < 8; ++t) {
            bfrag b = *reinterpret_cast<const bfrag*>(&Wls[16384 + ((t * 4 + ks) * 64 + lane) * 8]);
            acc[8 + t] = __builtin_amdgcn_mfma_f32_16x16x32_bf16(a[ks], b, acc[8 + t], 0, 0, 0);
        }
    }
#pragma unroll
    for (int r = 0; r < 4; ++r) {
        int row = row0 + q * 4 + r;
        if (row < N) {
            if (n < 4) es[(size_t)row * 4 + n] = accE[r];
            else if (n < 8) ed[(size_t)row * 4 + (n - 4)] = accE[r];
        }
    }
#pragma unroll
    for (int t = 0; t < 8; ++t) {
        int col = t * 16 + n;
#pragma unroll
        for (int r = 0; r < 4; ++r) {
            int row = row0 + q * 4 + r;
            if (row < N) {
                xwb[(size_t)row * 128 + col] = f2b(acc[t][r]);
                resb[(size_t)row * 128 + col] = f2b(acc[8 + t][r]);
            }
        }
    }
}

// ---------------- MFMA GEMM: [N,128]bf16 @ [128,cols+fold]bf16 ----------------
template <int COLT, int HEADS, int ESCOL>
__global__ __launch_bounds__(256) void gemm_mfma(
    const unsigned short* __restrict__ A, const unsigned short* __restrict__ Wg,
    unsigned short* __restrict__ out, int ldc, int cols,
    float* __restrict__ es, float* __restrict__ ed, int N) {
    __shared__ __align__(16) unsigned short Wls[COLT * 2048];
    int tid = threadIdx.x;
    {
        const float4* src = (const float4*)Wg;
        float4* dst = (float4*)Wls;
#pragma unroll
        for (int i = 0; i < COLT; ++i) dst[tid + i * 256] = src[tid + i * 256];
    }
    __syncthreads();
    int w = tid >> 6, lane = tid & 63;
    int n = lane & 15, q = lane >> 4;
    int row0 = blockIdx.x * 64 + w * 16;
    int ar = row0 + n; ar = ar < N ? ar : N - 1;   // clamp: OOB rows harmless
    f32x4 acc[COLT];
#pragma unroll
    for (int t = 0; t < COLT; ++t) acc[t] = (f32x4){0.f, 0.f, 0.f, 0.f};
    const unsigned short* arow = A + (size_t)ar * 128;
#pragma unroll
    for (int ks = 0; ks < 4; ++ks) {
        bfrag a = *reinterpret_cast<const bfrag*>(arow + ks * 32 + q * 8);
#pragma unroll
        for (int t = 0; t < COLT; ++t) {
            bfrag b = *reinterpret_cast<const bfrag*>(&Wls[((t * 4 + ks) * 64 + lane) * 8]);
            acc[t] = __builtin_amdgcn_mfma_f32_16x16x32_bf16(a, b, acc[t], 0, 0, 0);
        }
    }
    constexpr int TE = ESCOL >> 4, NE = ESCOL & 15;
    int dn = n - NE;
#pragma unroll
    for (int r = 0; r < 4; ++r) {
        int row = row0 + q * 4 + r;
        if (row < N) {
            if (dn >= 0 && dn < HEADS) es[(size_t)row * HEADS + dn] = acc[TE][r];
            else if (dn >= HEADS && dn < 2 * HEADS)
                ed[(size_t)row * HEADS + (dn - HEADS)] = acc[TE][r];
        }
    }
#pragma unroll
    for (int t = 0; t < COLT; ++t) {
        int col = t * 16 + n;
        if (col < cols) {
#pragma unroll
            for (int r = 0; r < 4; ++r) {
                int row = row0 + q * 4 + r;
                if (row < N) out[(size_t)row * ldc + col] = f2b(acc[t][r]);
            }
        }
    }
}

// ---------------- agg layers 1-2 + fused BN/bias/residual/ELU ----------------
// v2 lane mapping: 4 edge-subgroups (eg=lane>>4) x 16 channel-lanes (cp=lane&15).
// Each lane: 16B row slice (8ch) of its subgroup's edge; weight computed for
// 4 edges/chunk instead of 16; final shfl_xor(16,32) merge of 9 registers.
__global__ __launch_bounds__(256) void agg128_fused(
    const unsigned short* __restrict__ xwb, const float* __restrict__ es,
    const float* __restrict__ ed, const int* __restrict__ row_ptr,
    const int* __restrict__ csr, const float* __restrict__ bnsc,
    const float* __restrict__ bnsh, const unsigned short* __restrict__ resb,
    unsigned short* __restrict__ outb, int N) {
    int w = threadIdx.x >> 6, lane = threadIdx.x & 63;
    int node = blockIdx.x * 4 + w;
    if (node >= N) return;
    int eg = lane >> 4;        // edge subgroup 0..3
    int cp = lane & 15;        // channel-pack id
    int c0 = cp * 8;           // 8 channels per lane
    int h = cp >> 2;           // head = c0/32
    float edl = ed[node * 4 + h];
    // hoisted independent epilogue loads (overlap with gather chain)
    float4 scA = *(const float4*)(bnsc + c0);
    float4 scB = *(const float4*)(bnsc + c0 + 4);
    float4 shA = *(const float4*)(bnsh + c0);
    float4 shB = *(const float4*)(bnsh + c0 + 4);
    bfrag ur = *(const bfrag*)(resb + (size_t)node * 128 + c0);
    int start = __builtin_amdgcn_readfirstlane(row_ptr[node]);
    int end = __builtin_amdgcn_readfirstlane(row_ptr[node + 1]);
    float den = 0.f;
    float acc[8];
#pragma unroll
    for (int i = 0; i < 8; ++i) acc[i] = 0.f;
    for (int jb = start; jb < end; jb += 16) {
        int su[4];
#pragma unroll
        for (int u4 = 0; u4 < 4; ++u4) {
            int idx = jb + u4 * 4 + eg;
            idx = idx < end - 1 ? idx : end - 1;   // clamp (pad -> dup, L1 hit)
            su[u4] = csr[idx];
        }
        bfrag uu[4];
        float ev[4];
#pragma unroll
        for (int u4 = 0; u4 < 4; ++u4) {
            uu[u4] = *(const bfrag*)(xwb + (size_t)su[u4] * 128 + c0);
            ev[u4] = es[su[u4] * 4 + h];
        }
#pragma unroll
        for (int u4 = 0; u4 < 4; ++u4) {
            float e = ev[u4] + edl;
            e = e > 0.f ? e : 0.2f * e;
            float wg = __expf(e);
            wg = (jb + u4 * 4 + eg < end) ? wg : 0.f;
            den += wg;
#pragma unroll
            for (int i = 0; i < 8; ++i)
                acc[i] = fmaf(wg, b2f((unsigned short)uu[u4][i]), acc[i]);
        }
    }
    // merge the 4 edge subgroups (lanes eg differ; cp identical)
#pragma unroll
    for (int o = 16; o <= 32; o <<= 1) {
        den += __shfl_xor(den, o, 64);
#pragma unroll
        for (int i = 0; i < 8; ++i) acc[i] += __shfl_xor(acc[i], o, 64);
    }
    if (eg == 0) {
        float inv = 1.f / den;
        float scv[8] = {scA.x, scA.y, scA.z, scA.w, scB.x, scB.y, scB.z, scB.w};
        float shv[8] = {shA.x, shA.y, shA.z, shA.w, shB.x, shB.y, shB.z, shB.w};
        bfrag pk;
#pragma unroll
        for (int i = 0; i < 8; ++i) {
            float v = fmaf(acc[i] * inv, scv[i], shv[i]) + b2f((unsigned short)ur[i]);
            v = v > 0.f ? v : expm1f(v);
            pk[i] = (short)f2b(v);
        }
        *(bfrag*)(outb + (size_t)node * 128 + c0) = pk;
    }
}

// ---------------- layer-3 agg (H=1, 40ch) ----------------
__global__ __launch_bounds__(256) void agg40_kernel(
    const unsigned short* __restrict__ xw3b, const float* __restrict__ es3,
    const float* __restrict__ ed3, const int* __restrict__ row_ptr,
    const int* __restrict__ csr, const float* __restrict__ b3,
    void* __restrict__ out, const int* __restrict__ flag, int N) {
    int w = threadIdx.x >> 6, lane = threadIdx.x & 63;
    int node = blockIdx.x * 4 + w;
    if (node >= N) return;
    int i16 = lane & 15;
    int g = lane >= 40 ? 2 : (lane >= 20 ? 1 : 0);
    int cp = lane - g * 20;
    int c0 = cp * 2; c0 = c0 > 38 ? 38 : c0;
    // hoisted independent loads
    float edl = ed3[node];
    float b30 = b3[c0], b31 = b3[c0 + 1];
    int start = row_ptr[node], end = row_ptr[node + 1];
    float den = 0.f, a0 = 0.f, a1 = 0.f;
    for (int jb = start; jb < end; jb += 16) {
        int cnt = end - jb; cnt = cnt < 16 ? cnt : 16;
        int sv = csr[jb + (i16 < cnt ? i16 : 0)];
        unsigned uu[6];
#pragma unroll
        for (int t = 0; t < 6; ++t) {
            int slot = 3 * t + g; slot = slot < 15 ? slot : 15;
            int s = __shfl(sv, slot, 64);
            uu[t] = *(const unsigned*)(xw3b + (size_t)s * 40 + c0);
        }
        float wgl = 0.f;
        if (i16 < cnt) {
            float e = es3[sv] + edl;
            e = e > 0.f ? e : 0.2f * e;
            wgl = __expf(e);
        }
        float d = wgl;
        d += __shfl_xor(d, 1, 64);
        d += __shfl_xor(d, 2, 64);
        d += __shfl_xor(d, 4, 64);
        d += __shfl_xor(d, 8, 64);
        den += d;
#pragma unroll
        for (int t = 0; t < 6; ++t) {
            int slot = 3 * t + g;
            int sl = slot < 15 ? slot : 15;
            float wg = __shfl(wgl, sl, 64);
            if (slot >= cnt) wg = 0.f;
            a0 = fmaf(wg, __uint_as_float(uu[t] << 16), a0);
            a1 = fmaf(wg, __uint_as_float(uu[t] & 0xffff0000u), a1);
        }
    }
    float t0 = __shfl(a0, (lane + 20) & 63, 64);
    float t1 = __shfl(a0, (lane + 40) & 63, 64);
    float u0 = __shfl(a1, (lane + 20) & 63, 64);
    float u1 = __shfl(a1, (lane + 40) & 63, 64);
    a0 += t0 + t1;
    a1 += u0 + u1;
    if (lane < 20) {
        float inv = 1.f / den;
        float v0 = a0 * inv + b30;
        float v1 = a1 * inv + b31;
        size_t eoff = (size_t)node * 40 + c0;
        if (*flag) {
            unsigned pk = (unsigned)f2b(v0) | ((unsigned)f2b(v1) << 16);
            *(unsigned*)((unsigned short*)out + eoff) = pk;
        } else {
            *(float2*)((float*)out + eoff) = make_float2(v0, v1);
        }
    }
}

extern "C" void kernel_launch(void* const* d_in, const int* in_sizes, int n_in,
                              void* d_out, int out_size, void* d_ws, size_t ws_size,
                              hipStream_t stream) {
    (void)n_in; (void)out_size; (void)ws_size;
    const int N = in_sizes[0] / 128;
    const int E = in_sizes[1] / 2;
    const int EPN = E + N;
    const int NB = (N + 255) / 256;
    const int DB = (EPN + 511) / 512;     // 2 edges/thread blocks
    char* base = (char*)d_ws;
    size_t off = 0;
    auto alloc = [&](size_t bytes) -> char* {
        char* p = base + off;
        off = (off + bytes + 255) & ~(size_t)255;
        return p;
    };
    int* flag = (int*)alloc(4);
    int* deg8 = (int*)alloc((size_t)N * 8 * 4);     // zeroed each launch
    int* posk = (int*)alloc((size_t)N * 8 * 4);
    int* row_ptr = (int*)alloc((size_t)(N + 1) * 4);
    int* bsum = (int*)alloc((size_t)NB * 4);
    int* boff = (int*)alloc((size_t)NB * 4);
    int* csr = (int*)alloc((size_t)EPN * 4);
    float* bnsc1 = (float*)alloc(512); float* bnsh1 = (float*)alloc(512);
    float* bnsc2 = (float*)alloc(512); float* bnsh2 = (float*)alloc(512);
    float* B3f = (float*)alloc(256);
    unsigned short* Wl1 = (unsigned short*)alloc(36864);  // 9 tiles
    unsigned short* Wl2 = (unsigned short*)alloc(36864);  // 9 tiles
    unsigned short* WlR = (unsigned short*)alloc(32768);  // 8 tiles
    unsigned short* Wl3 = (unsigned short*)alloc(12288);  // 3 tiles
    unsigned short* xwb = (unsigned short*)alloc((size_t)N * 128 * 2);  // also xw3
    unsigned short* h1b = (unsigned short*)alloc((size_t)N * 128 * 2);
    unsigned short* resb = (unsigned short*)alloc((size_t)N * 128 * 2); // later h2b
    float* es = (float*)alloc((size_t)N * 4 * 4);   // [node*4+h]
    float* ed = (float*)alloc((size_t)N * 4 * 4);

    const int* ei = (const int*)d_in[1];

    hipMemsetAsync(deg8, 0, (size_t)N * 8 * 4, stream);

    InPtrs ip;
    for (int t = 0; t < 23; t++) ip.p[t] = d_in[t];
    prep_kernel<<<30 + DB, THREADS, 0, stream>>>(ip, flag, Wl1, Wl2, WlR, Wl3,
                                                 bnsc1, bnsh1, bnsc2, bnsh2,
                                                 B3f, N, ei, deg8, E, DB);

    bsum_kernel<<<NB, 256, 0, stream>>>(deg8, bsum, N);
    bscan_kernel<<<1, 1024, 0, stream>>>(bsum, boff, NB);
    scanw_kernel<<<NB, 256, 0, stream>>>(deg8, boff, row_ptr, posk, N);

    int gemmGrid = (N + 63) / 64;
    int aggGrid = (N + 3) / 4;

    // layer 1 GEMM fused with CSR scatter (independent work, one dispatch)
    fused_sg<<<gemmGrid + DB, 256, 0, stream>>>(d_in[0], flag, Wl1, WlR,
                                                xwb, resb, es, ed,
                                                ei, posk, csr, E, N, gemmGrid, DB);
    agg128_fused<<<aggGrid, 256, 0, stream>>>(xwb, es, ed, row_ptr, csr,
                                              bnsc1, bnsh1, resb, h1b, N);
    // layer 2
    gemm_mfma<9, 4, 128><<<gemmGrid, 256, 0, stream>>>(
        h1b, Wl2, xwb, 128, 128, es, ed, N);
    unsigned short* h2b = resb;  // resb free after layer-1 agg
    agg128_fused<<<aggGrid, 256, 0, stream>>>(xwb, es, ed, row_ptr, csr,
                                              bnsc2, bnsh2, h1b, h2b, N);
    // layer 3 (es/ed folded into cols 40,41 of tile 2)
    gemm_mfma<3, 1, 40><<<gemmGrid, 256, 0, stream>>>(
        h2b, Wl3, xwb, 40, 40, es, ed, N);
    agg40_kernel<<<aggGrid, 256, 0, stream>>>(xwb, es, ed, row_ptr, csr, B3f,
                                              d_out, flag, N);
}

// Round 22
// 273.727 us; speedup vs baseline: 1.0335x; 1.0237x over previous
//
#include <hip/hip_runtime.h>
#include <hip/hip_bf16.h>

#define THREADS 256

typedef __attribute__((ext_vector_type(8))) short bfrag;     // 8 bf16 = 4 VGPR
typedef __attribute__((ext_vector_type(4))) float f32x4;     // MFMA accumulator

__device__ inline unsigned short f2b(float v) {
    __hip_bfloat16 b = __float2bfloat16(v);
    return *reinterpret_cast<unsigned short*>(&b);
}
__device__ inline float b2f(unsigned short u) {
    return __uint_as_float(((unsigned)u) << 16);
}
__device__ inline float rdv(const void* p, int off, bool isbf) {
    return isbf ? b2f(((const unsigned short*)p)[off]) : ((const float*)p)[off];
}
// 8-element contiguous dot (vector loads, both operands 16B-aligned offsets)
__device__ inline float dot8(const void* W, const void* av, int wbase, int abase, bool isbf) {
    if (isbf) {
        const unsigned short* wp = (const unsigned short*)W + wbase;
        const unsigned short* ap = (const unsigned short*)av + abase;
        ushort4 w0 = *(const ushort4*)wp, w1 = *(const ushort4*)(wp + 4);
        ushort4 a0 = *(const ushort4*)ap, a1 = *(const ushort4*)(ap + 4);
        return b2f(w0.x) * b2f(a0.x) + b2f(w0.y) * b2f(a0.y) +
               b2f(w0.z) * b2f(a0.z) + b2f(w0.w) * b2f(a0.w) +
               b2f(w1.x) * b2f(a1.x) + b2f(w1.y) * b2f(a1.y) +
               b2f(w1.z) * b2f(a1.z) + b2f(w1.w) * b2f(a1.w);
    } else {
        const float* wp = (const float*)W + wbase;
        const float* ap = (const float*)av + abase;
        float4 w0 = *(const float4*)wp, w1 = *(const float4*)(wp + 4);
        float4 a0 = *(const float4*)ap, a1 = *(const float4*)(ap + 4);
        return w0.x * a0.x + w0.y * a0.y + w0.z * a0.z + w0.w * a0.w +
               w1.x * a1.x + w1.y * a1.y + w1.z * a1.z + w1.w * a1.w;
    }
}

struct InPtrs { const void* p[23]; };

// ---------------- fused prep: W->frag-order (+folded es/ed cols via LDS
// phase-A), BN fold, degree count (2 edges/thread). ---------------------------
__global__ void prep_kernel(InPtrs in, int* __restrict__ flag,
                            unsigned short* __restrict__ Wl1, unsigned short* __restrict__ Wl2,
                            unsigned short* __restrict__ WlR, unsigned short* __restrict__ Wl3,
                            float* __restrict__ bnsc1, float* __restrict__ bnsh1,
                            float* __restrict__ bnsc2, float* __restrict__ bnsh2,
                            float* __restrict__ B3f,
                            int N, const int* __restrict__ ei, int* __restrict__ deg8,
                            int E, int DB) {
    int b = blockIdx.x, tid = threadIdx.x;
    if (b >= 30) {
        int stride = DB * 256;
        for (int i = (b - 30) * 256 + tid; i < E + N; i += stride) {
            int d = (i < E) ? ei[E + i] : (i - E);
            int k = (i >> 10) & 7;
            atomicAdd(&deg8[k * N + d], 1);
        }
        return;
    }
    // dtype detect over first 4096 shorts (only these 30 blocks; L2-broadcast)
    __shared__ int sred[4];
    __shared__ float sWes[128 * 8];
    const unsigned short* x = (const unsigned short*)in.p[0];
    int local = 0;
    for (int i = tid; i < 4096; i += 256) {
        unsigned ex = (x[i] >> 7) & 0xFF;
        if (ex == 0xFF || ex >= 134 || (ex > 0 && ex <= 100)) local++;
    }
#pragma unroll
    for (int o = 1; o < 64; o <<= 1) local += __shfl_xor(local, o, 64);
    if ((tid & 63) == 0) sred[tid >> 6] = local;
    __syncthreads();
    bool isbf = !((sred[0] + sred[1] + sred[2] + sred[3]) * 8 > 4096);

    if (b < 29) {
        const void *Wv, *asp = 0, *adp = 0; unsigned short* o; int cols, FH = 0, tt;
        if (b < 9)       { Wv = in.p[2];  asp = in.p[3];  adp = in.p[4];  o = Wl1; cols = 128; FH = 4; tt = b; }
        else if (b < 18) { Wv = in.p[6];  asp = in.p[7];  adp = in.p[8];  o = Wl2; cols = 128; FH = 4; tt = b - 9; }
        else if (b < 26) { Wv = in.p[14];                                 o = WlR; cols = 128;         tt = b - 18; }
        else             { Wv = in.p[10]; asp = in.p[11]; adp = in.p[12]; o = Wl3; cols = 40;  FH = 1; tt = b - 26; }
        // ---- phase A: cooperative fold (parallel dots, vector loads) ----
        bool foldblk = (FH == 4 && tt == 8) || (FH == 1 && tt == 2);
        if (foldblk) {
            if (FH == 4) {
#pragma unroll
                for (int u = 0; u < 4; ++u) {
                    int od = tid * 4 + u;
                    int k = od >> 3, dn = od & 7;
                    int h = dn < 4 ? dn : dn - 4;
                    const void* av = dn < 4 ? asp : adp;
                    float s = 0.f;
#pragma unroll
                    for (int cc = 0; cc < 32; cc += 8)
                        s += dot8(Wv, av, k * 128 + h * 32 + cc, h * 32 + cc, isbf);
                    sWes[k * 8 + dn] = s;
                }
            } else {
                int k = tid >> 1, dn = tid & 1;
                const void* av = dn ? adp : asp;
                float s = 0.f;
#pragma unroll
                for (int cc = 0; cc < 40; cc += 8)
                    s += dot8(Wv, av, k * 40 + cc, cc, isbf);
                sWes[k * 8 + dn] = s;
            }
            __syncthreads();
        }
        // ---- phase B: fragment-order write ----
        int id = tt * 256 + tid;
        int ks = (id >> 6) & 3, l = id & 63;
        int q = l >> 4, n = l & 15;
        int c = tt * 16 + n;
#pragma unroll
        for (int j = 0; j < 8; ++j) {
            int k = ks * 32 + q * 8 + j;
            float v = 0.f;
            if (c < cols) v = rdv(Wv, k * cols + c, isbf);
            else if (FH && c < cols + 2 * FH) v = sWes[k * 8 + (c - cols)];
            o[id * 8 + j] = f2b(v);
        }
    } else {
        int c = tid;
        if (c < 128) {
            float s = rdv(in.p[15], c, isbf) * rsqrtf(rdv(in.p[18], c, isbf) + 1e-5f);
            bnsc1[c] = s;
            bnsh1[c] = rdv(in.p[16], c, isbf) - rdv(in.p[17], c, isbf) * s +
                       rdv(in.p[5], c, isbf) * s;
        } else {
            int d = c - 128;
            float s = rdv(in.p[19], d, isbf) * rsqrtf(rdv(in.p[22], d, isbf) + 1e-5f);
            bnsc2[d] = s;
            bnsh2[d] = rdv(in.p[20], d, isbf) - rdv(in.p[21], d, isbf) * s +
                       rdv(in.p[9], d, isbf) * s;
            if (d < 40) B3f[d] = rdv(in.p[13], d, isbf);
        }
        if (tid == 0) *flag = isbf ? 1 : 0;
    }
}

// ---------------- CSR scan stages (8-copy aware) ----------------
__global__ void bsum_kernel(const int* __restrict__ deg8, int* __restrict__ bsum, int N) {
    int idx = blockIdx.x * 256 + threadIdx.x;
    int lane = threadIdx.x & 63, wv = threadIdx.x >> 6;
    int v = 0;
    if (idx < N) {
#pragma unroll
        for (int k = 0; k < 8; ++k) v += deg8[k * N + idx];
    }
#pragma unroll
    for (int o = 1; o < 64; o <<= 1) v += __shfl_xor(v, o, 64);
    __shared__ int ws[4];
    if (lane == 0) ws[wv] = v;
    __syncthreads();
    if (threadIdx.x == 0) bsum[blockIdx.x] = ws[0] + ws[1] + ws[2] + ws[3];
}

__global__ __launch_bounds__(1024) void bscan_kernel(const int* __restrict__ bsum,
                                                     int* __restrict__ boff, int nb) {
    __shared__ int ws[16];
    int tid = threadIdx.x, lane = tid & 63, wv = tid >> 6;
    int v = (tid < nb) ? bsum[tid] : 0;
    int sc = v;
#pragma unroll
    for (int o = 1; o < 64; o <<= 1) {
        int t = __shfl_up(sc, o, 64);
        if (lane >= o) sc += t;
    }
    if (lane == 63) ws[wv] = sc;
    __syncthreads();
    int add = 0;
#pragma unroll
    for (int k = 0; k < 16; ++k) add += (k < wv) ? ws[k] : 0;
    if (tid < nb) boff[tid] = add + sc - v;
}

__global__ void scanw_kernel(const int* __restrict__ deg8, const int* __restrict__ boff,
                             int* __restrict__ row_ptr, int* __restrict__ posk, int N) {
    int idx = blockIdx.x * 256 + threadIdx.x;
    int lane = threadIdx.x & 63, wv = threadIdx.x >> 6;
    int vk[8];
    int v = 0;
    if (idx < N) {
#pragma unroll
        for (int k = 0; k < 8; ++k) { vk[k] = deg8[k * N + idx]; v += vk[k]; }
    } else {
#pragma unroll
        for (int k = 0; k < 8; ++k) vk[k] = 0;
    }
    int sc = v;
#pragma unroll
    for (int o = 1; o < 64; o <<= 1) {
        int t = __shfl_up(sc, o, 64);
        if (lane >= o) sc += t;
    }
    __shared__ int ws[4];
    if (lane == 63) ws[wv] = sc;
    __syncthreads();
    int add = boff[blockIdx.x];
#pragma unroll
    for (int k = 0; k < 4; ++k) add += (k < wv) ? ws[k] : 0;
    int excl = add + sc - v;
    if (idx < N) {
        row_ptr[idx + 1] = excl + v;
        int run = excl;
#pragma unroll
        for (int k = 0; k < 8; ++k) { posk[k * N + idx] = run; run += vk[k]; }
    }
    if (idx == 0) row_ptr[0] = 0;
}

// ---------------- fused: gemm_dual (blocks < GG) ∥ scatter (blocks >= GG) ----
// Both halves proven standalone (r5/r7). Scatter blocks early-return pre-LDS.
__global__ __launch_bounds__(256) void fused_sg(
    const void* __restrict__ Ain, const int* __restrict__ flag,
    const unsigned short* __restrict__ Wg1, const unsigned short* __restrict__ WgR,
    unsigned short* __restrict__ xwb, unsigned short* __restrict__ resb,
    float* __restrict__ es, float* __restrict__ ed,
    const int* __restrict__ ei, int* __restrict__ posk, int* __restrict__ csr,
    int E, int N, int GG, int DB) {
    int tid = threadIdx.x;
    if ((int)blockIdx.x >= GG) {
        // ---- scatter: same k mapping + index space as degree count ----
        int sb = blockIdx.x - GG;
        int stride = DB * 256;
        for (int i = sb * 256 + tid; i < E + N; i += stride) {
            int s, d;
            if (i < E) { s = ei[i]; d = ei[E + i]; }
            else { s = i - E; d = s; }
            int k = (i >> 10) & 7;
            int p = atomicAdd(&posk[k * N + d], 1);
            csr[p] = s;
        }
        return;
    }
    __shared__ __align__(16) unsigned short Wls[16 * 2048];
    {
        const float4* s1 = (const float4*)Wg1;
        const float4* s2 = (const float4*)WgR;
        float4* dst = (float4*)Wls;
#pragma unroll
        for (int i = 0; i < 8; ++i) dst[tid + i * 256] = s1[tid + i * 256];
#pragma unroll
        for (int i = 0; i < 8; ++i) dst[2048 + tid + i * 256] = s2[tid + i * 256];
    }
    bool isbf = (*flag != 0);
    __syncthreads();
    int w = tid >> 6, lane = tid & 63;
    int n = lane & 15, q = lane >> 4;
    int row0 = blockIdx.x * 64 + w * 16;
    int ar = row0 + n; ar = ar < N ? ar : N - 1;
    bfrag a[4];
    if (isbf) {
        const unsigned short* arow = (const unsigned short*)Ain + (size_t)ar * 128;
#pragma unroll
        for (int ks = 0; ks < 4; ++ks)
            a[ks] = *reinterpret_cast<const bfrag*>(arow + ks * 32 + q * 8);
    } else {
        const float* arow = (const float*)Ain + (size_t)ar * 128;
#pragma unroll
        for (int ks = 0; ks < 4; ++ks) {
            float4 f0 = *reinterpret_cast<const float4*>(arow + ks * 32 + q * 8);
            float4 f1 = *reinterpret_cast<const float4*>(arow + ks * 32 + q * 8 + 4);
            bfrag t;
            t[0] = (short)f2b(f0.x); t[1] = (short)f2b(f0.y);
            t[2] = (short)f2b(f0.z); t[3] = (short)f2b(f0.w);
            t[4] = (short)f2b(f1.x); t[5] = (short)f2b(f1.y);
            t[6] = (short)f2b(f1.z); t[7] = (short)f2b(f1.w);
            a[ks] = t;
        }
    }
    f32x4 acc[16], accE;
#pragma unroll
    for (int t = 0; t < 16; ++t) acc[t] = (f32x4){0.f, 0.f, 0.f, 0.f};
    accE = (f32x4){0.f, 0.f, 0.f, 0.f};
#pragma unroll
    for (int ks = 0; ks < 4; ++ks) {
#pragma unroll
        for (int t = 0; t < 8; ++t) {
            bfrag b = *reinterpret_cast<const bfrag*>(&Wls[((t * 4 + ks) * 64 + lane) * 8]);
            acc[t] = __builtin_amdgcn_mfma_f32_16x16x32_bf16(a[ks], b, acc[t], 0, 0, 0);
        }
        // folded es/ed tile read straight from global (L2-hot broadcast)
        bfrag be = *reinterpret_cast<const bfrag*>(Wg1 + ((size_t)(32 + ks) * 64 + lane) * 8);
        accE = __builtin_amdgcn_mfma_f32_16x16x32_bf16(a[ks], be, accE, 0, 0, 0);
#pragma unroll
        for (int t = 0; t < 8; ++t) {
            bfrag b = *reinterpret_cast<const bfrag*>(&Wls[16384 + ((t * 4 + ks) * 64 + lane) * 8]);
            acc[8 + t] = __builtin_amdgcn_mfma_f32_16x16x32_bf16(a[ks], b, acc[8 + t], 0, 0, 0);
        }
    }
#pragma unroll
    for (int r = 0; r < 4; ++r) {
        int row = row0 + q * 4 + r;
        if (row < N) {
            if (n < 4) es[(size_t)row * 4 + n] = accE[r];
            else if (n < 8) ed[(size_t)row * 4 + (n - 4)] = accE[r];
        }
    }
#pragma unroll
    for (int t = 0; t < 8; ++t) {
        int col = t * 16 + n;
#pragma unroll
        for (int r = 0; r < 4; ++r) {
            int row = row0 + q * 4 + r;
            if (row < N) {
                xwb[(size_t)row * 128 + col] = f2b(acc[t][r]);
                resb[(size_t)row * 128 + col] = f2b(acc[8 + t][r]);
            }
        }
    }
}

// ---------------- MFMA GEMM: [N,128]bf16 @ [128,cols+fold]bf16 ----------------
// es/ed come out of MFMA tile TE (folded weight columns) -> no shfl epilogue.
template <int COLT, int HEADS, int ESCOL>
__global__ __launch_bounds__(256) void gemm_mfma(
    const unsigned short* __restrict__ A, const unsigned short* __restrict__ Wg,
    unsigned short* __restrict__ out, int ldc, int cols,
    float* __restrict__ es, float* __restrict__ ed, int N) {
    __shared__ __align__(16) unsigned short Wls[COLT * 2048];
    int tid = threadIdx.x;
    {
        const float4* src = (const float4*)Wg;
        float4* dst = (float4*)Wls;
#pragma unroll
        for (int i = 0; i < COLT; ++i) dst[tid + i * 256] = src[tid + i * 256];
    }
    __syncthreads();
    int w = tid >> 6, lane = tid & 63;
    int n = lane & 15, q = lane >> 4;
    int row0 = blockIdx.x * 64 + w * 16;
    int ar = row0 + n; ar = ar < N ? ar : N - 1;   // clamp: OOB rows harmless
    f32x4 acc[COLT];
#pragma unroll
    for (int t = 0; t < COLT; ++t) acc[t] = (f32x4){0.f, 0.f, 0.f, 0.f};
    const unsigned short* arow = A + (size_t)ar * 128;
#pragma unroll
    for (int ks = 0; ks < 4; ++ks) {
        bfrag a = *reinterpret_cast<const bfrag*>(arow + ks * 32 + q * 8);
#pragma unroll
        for (int t = 0; t < COLT; ++t) {
            bfrag b = *reinterpret_cast<const bfrag*>(&Wls[((t * 4 + ks) * 64 + lane) * 8]);
            acc[t] = __builtin_amdgcn_mfma_f32_16x16x32_bf16(a, b, acc[t], 0, 0, 0);
        }
    }
    constexpr int TE = ESCOL >> 4, NE = ESCOL & 15;
    int dn = n - NE;
#pragma unroll
    for (int r = 0; r < 4; ++r) {
        int row = row0 + q * 4 + r;
        if (row < N) {
            if (dn >= 0 && dn < HEADS) es[(size_t)row * HEADS + dn] = acc[TE][r];
            else if (dn >= HEADS && dn < 2 * HEADS)
                ed[(size_t)row * HEADS + (dn - HEADS)] = acc[TE][r];
        }
    }
#pragma unroll
    for (int t = 0; t < COLT; ++t) {
        int col = t * 16 + n;
        if (col < cols) {
#pragma unroll
            for (int r = 0; r < 4; ++r) {
                int row = row0 + q * 4 + r;
                if (row < N) out[(size_t)row * ldc + col] = f2b(acc[t][r]);
            }
        }
    }
}

// ---------------- agg layers 1-2 + fused BN/bias/residual/ELU ----------------
__global__ __launch_bounds__(256) void agg128_fused(
    const unsigned short* __restrict__ xwb, const float* __restrict__ es,
    const float* __restrict__ ed, const int* __restrict__ row_ptr,
    const int* __restrict__ csr, const float* __restrict__ bnsc,
    const float* __restrict__ bnsh, const unsigned short* __restrict__ resb,
    unsigned short* __restrict__ outb, int N) {
    int w = threadIdx.x >> 6, lane = threadIdx.x & 63;
    int node = blockIdx.x * 4 + w;
    if (node >= N) return;
    int h = lane >> 4;
    int c0 = lane * 2;
    float edl = ed[node * 4 + h];
    int start = __builtin_amdgcn_readfirstlane(row_ptr[node]);
    int end = __builtin_amdgcn_readfirstlane(row_ptr[node + 1]);
    float den = 0.f, a0 = 0.f, a1 = 0.f;
    for (int jb = start; jb < end; jb += 16) {
        int su[16];
#pragma unroll
        for (int u = 0; u < 16; ++u) {
            int idx = jb + u;
            idx = idx < end - 1 ? idx : end - 1;
            su[u] = csr[idx];                       // uniform addr -> s_load
        }
        unsigned uu[16];
        float ev[16];
#pragma unroll
        for (int u = 0; u < 16; ++u) {
            uu[u] = *(const unsigned*)(xwb + (size_t)su[u] * 128 + c0);
            ev[u] = es[su[u] * 4 + h];
        }
#pragma unroll
        for (int u = 0; u < 16; ++u) {
            float e = ev[u] + edl;
            e = e > 0.f ? e : 0.2f * e;
            float wg = __expf(e);
            wg = (jb + u < end) ? wg : 0.f;         // uniform cond, branch-free
            den += wg;
            a0 = fmaf(wg, __uint_as_float(uu[u] << 16), a0);
            a1 = fmaf(wg, __uint_as_float(uu[u] & 0xffff0000u), a1);
        }
    }
    float inv = 1.f / den;
    float2 sc = *(const float2*)(bnsc + c0);
    float2 sh = *(const float2*)(bnsh + c0);
    unsigned ur = *(const unsigned*)(resb + (size_t)node * 128 + c0);
    float v0 = fmaf(a0 * inv, sc.x, sh.x) + __uint_as_float(ur << 16);
    float v1 = fmaf(a1 * inv, sc.y, sh.y) + __uint_as_float(ur & 0xffff0000u);
    v0 = v0 > 0.f ? v0 : expm1f(v0);
    v1 = v1 > 0.f ? v1 : expm1f(v1);
    unsigned pk = (unsigned)f2b(v0) | ((unsigned)f2b(v1) << 16);
    *(unsigned*)(outb + (size_t)node * 128 + c0) = pk;
}

// ---------------- layer-3 agg (H=1, 40ch) ----------------
__global__ __launch_bounds__(256) void agg40_kernel(
    const unsigned short* __restrict__ xw3b, const float* __restrict__ es3,
    const float* __restrict__ ed3, const int* __restrict__ row_ptr,
    const int* __restrict__ csr, const float* __restrict__ b3,
    void* __restrict__ out, const int* __restrict__ flag, int N) {
    int w = threadIdx.x >> 6, lane = threadIdx.x & 63;
    int node = blockIdx.x * 4 + w;
    if (node >= N) return;
    int i16 = lane & 15;
    int g = lane >= 40 ? 2 : (lane >= 20 ? 1 : 0);
    int cp = lane - g * 20;
    int c0 = cp * 2; c0 = c0 > 38 ? 38 : c0;
    float edl = ed3[node];
    int start = row_ptr[node], end = row_ptr[node + 1];
    float den = 0.f, a0 = 0.f, a1 = 0.f;
    for (int jb = start; jb < end; jb += 16) {
        int cnt = end - jb; cnt = cnt < 16 ? cnt : 16;
        int sv = csr[jb + (i16 < cnt ? i16 : 0)];
        unsigned uu[6];
#pragma unroll
        for (int t = 0; t < 6; ++t) {
            int slot = 3 * t + g; slot = slot < 15 ? slot : 15;
            int s = __shfl(sv, slot, 64);
            uu[t] = *(const unsigned*)(xw3b + (size_t)s * 40 + c0);
        }
        float wgl = 0.f;
        if (i16 < cnt) {
            float e = es3[sv] + edl;
            e = e > 0.f ? e : 0.2f * e;
            wgl = __expf(e);
        }
        float d = wgl;
        d += __shfl_xor(d, 1, 64);
        d += __shfl_xor(d, 2, 64);
        d += __shfl_xor(d, 4, 64);
        d += __shfl_xor(d, 8, 64);
        den += d;
#pragma unroll
        for (int t = 0; t < 6; ++t) {
            int slot = 3 * t + g;
            int sl = slot < 15 ? slot : 15;
            float wg = __shfl(wgl, sl, 64);
            if (slot >= cnt) wg = 0.f;
            a0 = fmaf(wg, __uint_as_float(uu[t] << 16), a0);
            a1 = fmaf(wg, __uint_as_float(uu[t] & 0xffff0000u), a1);
        }
    }
    float t0 = __shfl(a0, (lane + 20) & 63, 64);
    float t1 = __shfl(a0, (lane + 40) & 63, 64);
    float u0 = __shfl(a1, (lane + 20) & 63, 64);
    float u1 = __shfl(a1, (lane + 40) & 63, 64);
    a0 += t0 + t1;
    a1 += u0 + u1;
    if (lane < 20) {
        float inv = 1.f / den;
        float v0 = a0 * inv + b3[c0];
        float v1 = a1 * inv + b3[c0 + 1];
        size_t eoff = (size_t)node * 40 + c0;
        if (*flag) {
            unsigned pk = (unsigned)f2b(v0) | ((unsigned)f2b(v1) << 16);
            *(unsigned*)((unsigned short*)out + eoff) = pk;
        } else {
            *(float2*)((float*)out + eoff) = make_float2(v0, v1);
        }
    }
}

extern "C" void kernel_launch(void* const* d_in, const int* in_sizes, int n_in,
                              void* d_out, int out_size, void* d_ws, size_t ws_size,
                              hipStream_t stream) {
    (void)n_in; (void)out_size; (void)ws_size;
    const int N = in_sizes[0] / 128;
    const int E = in_sizes[1] / 2;
    const int EPN = E + N;
    const int NB = (N + 255) / 256;
    const int DB = (EPN + 511) / 512;     // 2 edges/thread blocks
    char* base = (char*)d_ws;
    size_t off = 0;
    auto alloc = [&](size_t bytes) -> char* {
        char* p = base + off;
        off = (off + bytes + 255) & ~(size_t)255;
        return p;
    };
    int* flag = (int*)alloc(4);
    int* deg8 = (int*)alloc((size_t)N * 8 * 4);     // zeroed each launch
    int* posk = (int*)alloc((size_t)N * 8 * 4);
    int* row_ptr = (int*)alloc((size_t)(N + 1) * 4);
    int* bsum = (int*)alloc((size_t)NB * 4);
    int* boff = (int*)alloc((size_t)NB * 4);
    int* csr = (int*)alloc((size_t)EPN * 4);
    float* bnsc1 = (float*)alloc(512); float* bnsh1 = (float*)alloc(512);
    float* bnsc2 = (float*)alloc(512); float* bnsh2 = (float*)alloc(512);
    float* B3f = (float*)alloc(256);
    unsigned short* Wl1 = (unsigned short*)alloc(36864);  // 9 tiles
    unsigned short* Wl2 = (unsigned short*)alloc(36864);  // 9 tiles
    unsigned short* WlR = (unsigned short*)alloc(32768);  // 8 tiles
    unsigned short* Wl3 = (unsigned short*)alloc(12288);  // 3 tiles
    unsigned short* xwb = (unsigned short*)alloc((size_t)N * 128 * 2);  // also xw3
    unsigned short* h1b = (unsigned short*)alloc((size_t)N * 128 * 2);
    unsigned short* resb = (unsigned short*)alloc((size_t)N * 128 * 2); // later h2b
    float* es = (float*)alloc((size_t)N * 4 * 4);   // [node*4+h]
    float* ed = (float*)alloc((size_t)N * 4 * 4);

    const int* ei = (const int*)d_in[1];

    hipMemsetAsync(deg8, 0, (size_t)N * 8 * 4, stream);

    InPtrs ip;
    for (int t = 0; t < 23; t++) ip.p[t] = d_in[t];
    prep_kernel<<<30 + DB, THREADS, 0, stream>>>(ip, flag, Wl1, Wl2, WlR, Wl3,
                                                 bnsc1, bnsh1, bnsc2, bnsh2,
                                                 B3f, N, ei, deg8, E, DB);

    bsum_kernel<<<NB, 256, 0, stream>>>(deg8, bsum, N);
    bscan_kernel<<<1, 1024, 0, stream>>>(bsum, boff, NB);
    scanw_kernel<<<NB, 256, 0, stream>>>(deg8, boff, row_ptr, posk, N);

    int gemmGrid = (N + 63) / 64;
    int aggGrid = (N + 3) / 4;

    // layer 1 GEMM fused with CSR scatter (independent work, one dispatch)
    fused_sg<<<gemmGrid + DB, 256, 0, stream>>>(d_in[0], flag, Wl1, WlR,
                                                xwb, resb, es, ed,
                                                ei, posk, csr, E, N, gemmGrid, DB);
    agg128_fused<<<aggGrid, 256, 0, stream>>>(xwb, es, ed, row_ptr, csr,
                                              bnsc1, bnsh1, resb, h1b, N);
    // layer 2
    gemm_mfma<9, 4, 128><<<gemmGrid, 256, 0, stream>>>(
        h1b, Wl2, xwb, 128, 128, es, ed, N);
    unsigned short* h2b = resb;  // resb free after layer-1 agg
    agg128_fused<<<aggGrid, 256, 0, stream>>>(xwb, es, ed, row_ptr, csr,
                                              bnsc2, bnsh2, h1b, h2b, N);
    // layer 3 (es/ed folded into cols 40,41 of tile 2)
    gemm_mfma<3, 1, 40><<<gemmGrid, 256, 0, stream>>>(
        h2b, Wl3, xwb, 40, 40, es, ed, N);
    agg40_kernel<<<aggGrid, 256, 0, stream>>>(xwb, es, ed, row_ptr, csr, B3f,
                                              d_out, flag, N);
}